// Round 7
// baseline (411.489 us; speedup 1.0000x reference)
//
#include <hip/hip_runtime.h>
#include <hip/hip_fp16.h>

namespace {
constexpr int NN   = 10000;   // nodes
constexpr int NE   = 640000;  // edges
constexpr int INC  = 128;     // input channels
constexpr int HIDC = 256;     // hidden channels
constexpr int OUTC = 10;      // output channels
constexpr int NG   = 64;      // graphs
constexpr int PP   = 8;       // pooling partials per graph
constexpr int HB   = 64;      // histogram blocks
}

typedef __attribute__((ext_vector_type(8))) short short8;
typedef __attribute__((ext_vector_type(4))) float f32x4;

__device__ __forceinline__ ushort f2bf(float f) {
    uint u = __float_as_uint(f);
    uint r = u + 0x7FFFu + ((u >> 16) & 1u);   // RNE
    return (ushort)(r >> 16);
}
__device__ __forceinline__ float bf2f(ushort u) {
    return __uint_as_float(((uint)u) << 16);
}
__device__ __forceinline__ float rec_w(uint rec) {
    return __half2float(__ushort_as_half((ushort)(rec & 0xFFFFu)));
}

// fp32 -> bf16, 4 elements/thread (x only; weights converted in GEMM staging)
__global__ __launch_bounds__(256) void f2bf_kernel(const float* __restrict__ in,
                                                   ushort* __restrict__ out, int n4) {
    int i = blockIdx.x * blockDim.x + threadIdx.x;
    if (i >= n4) return;
    float4 v = ((const float4*)in)[i];
    ushort4 o;
    o.x = f2bf(v.x); o.y = f2bf(v.y); o.z = f2bf(v.z); o.w = f2bf(v.w);
    ((ushort4*)out)[i] = o;
}

// ---- CSR build step 1: LDS-privatized histogram by dst ----
// HB blocks x 1024 thr; each block histograms NE/HB edges in 40KB LDS,
// then writes its private hist coalesced. No global atomics.
__global__ __launch_bounds__(1024) void hist_kernel(const int* __restrict__ ei,
                                                    int* __restrict__ hist_b) {
    __shared__ int h[NN];
    const int t = threadIdx.x;
    const int b = blockIdx.x;
    for (int i = t; i < NN; i += 1024) h[i] = 0;
    __syncthreads();
    constexpr int CHUNK = NE / HB;  // 10000
    const int base = NE + b * CHUNK;  // dst row of edge_index
    for (int i = t; i < CHUNK; i += 1024)
        atomicAdd(&h[ei[base + i]], 1);
    __syncthreads();
    for (int i = t; i < NN; i += 1024) hist_b[(size_t)b * NN + i] = h[i];
}

// ---- step 2: fold HB partial hists + exclusive scan -> row_start, cur ----
__global__ __launch_bounds__(1024) void scan_kernel(const int* __restrict__ hist_b,
                                                    int* __restrict__ row_start,
                                                    int* __restrict__ cur) {
    __shared__ int part[1024];
    const int t = threadIdx.x;
    constexpr int C = (NN + 1023) / 1024;  // 10
    const int base = t * C;
    int deg[C];
#pragma unroll
    for (int i = 0; i < C; i++) deg[i] = 0;
    for (int b = 0; b < HB; b++) {
        const int* row = hist_b + (size_t)b * NN;
#pragma unroll
        for (int i = 0; i < C; i++) {
            int idx = base + i;
            if (idx < NN) deg[i] += row[idx];
        }
    }
    int sum = 0;
#pragma unroll
    for (int i = 0; i < C; i++) sum += deg[i];
    part[t] = sum;
    __syncthreads();
    for (int off = 1; off < 1024; off <<= 1) {
        int v = (t >= off) ? part[t - off] : 0;
        __syncthreads();
        part[t] += v;
        __syncthreads();
    }
    int run = (t == 0) ? 0 : part[t - 1];
#pragma unroll
    for (int i = 0; i < C; i++) {
        int idx = base + i;
        if (idx < NN) {
            row_start[idx] = run;
            cur[idx] = run;
            run += deg[i];
        }
    }
    if (t == 1023) row_start[NN] = run;
}

// ---- step 3: bucket-scatter edges into CSR order: one packed 4B record ----
__global__ __launch_bounds__(256) void build_kernel(const int* __restrict__ ei,
                                                    const float* __restrict__ ew,
                                                    int* __restrict__ cur,
                                                    uint* __restrict__ erec) {
    int e = blockIdx.x * blockDim.x + threadIdx.x;
    if (e >= NE) return;
    int d = ei[NE + e];
    int pos = atomicAdd(&cur[d], 1);
    ushort hw = __half_as_ushort(__float2half(ew[e]));
    erec[pos] = ((uint)ei[e] << 16) | (uint)hw;
}

// ---- aggregation via CSR gather (bf16 in/out, fp32 accumulate) ----
// out[n] = x[n] + sum_e w_e * x[src_e]; one wave per node, 12-edge batches.
template <int F>
__global__ __launch_bounds__(256) void gather_bf16_kernel(const int* __restrict__ row_start,
                                                          const uint* __restrict__ erec,
                                                          const ushort* __restrict__ x,
                                                          ushort* __restrict__ out) {
    constexpr int VEC = F / 64;  // bf16 per lane: 2 (F=128) or 4 (F=256)
    constexpr int U = 12;
    const int n = blockIdx.x * 4 + (threadIdx.x >> 6);
    const int lane = threadIdx.x & 63;
    if (n >= NN) return;
    const int beg = row_start[n];
    const int end = row_start[n + 1];
    const size_t loff = (size_t)lane * VEC;

    float acc[VEC];
    {
        ushort v[VEC];
        if (VEC == 4) *(ushort4*)v = *(const ushort4*)(x + (size_t)n * F + loff);
        else          *(ushort2*)v = *(const ushort2*)(x + (size_t)n * F + loff);
#pragma unroll
        for (int i = 0; i < VEC; i++) acc[i] = bf2f(v[i]);
    }

    int e = beg;
    for (; e + U <= end; e += U) {
        uint rec[U];
#pragma unroll
        for (int u = 0; u < U; u++) rec[u] = erec[e + u];
        ushort v[U][VEC];
#pragma unroll
        for (int u = 0; u < U; u++) {
            const ushort* r = x + (size_t)(rec[u] >> 16) * F + loff;
            if (VEC == 4) *(ushort4*)v[u] = *(const ushort4*)r;
            else          *(ushort2*)v[u] = *(const ushort2*)r;
        }
#pragma unroll
        for (int u = 0; u < U; u++) {
            const float w = rec_w(rec[u]);
#pragma unroll
            for (int i = 0; i < VEC; i++) acc[i] += w * bf2f(v[u][i]);
        }
    }
    for (; e < end; e++) {
        uint rec = erec[e];
        const float w = rec_w(rec);
        ushort v[VEC];
        const ushort* r = x + (size_t)(rec >> 16) * F + loff;
        if (VEC == 4) *(ushort4*)v = *(const ushort4*)r;
        else          *(ushort2*)v = *(const ushort2*)r;
#pragma unroll
        for (int i = 0; i < VEC; i++) acc[i] += w * bf2f(v[i]);
    }

    ushort o[VEC];
#pragma unroll
    for (int i = 0; i < VEC; i++) o[i] = f2bf(acc[i]);
    if (VEC == 4) *(ushort4*)(out + (size_t)n * F + loff) = *(ushort4*)o;
    else          *(ushort2*)(out + (size_t)n * F + loff) = *(ushort2*)o;
}

// ---- MFMA bf16 GEMM: C[M,256] = relu(A[M,K] @ W[256,K]^T + bias), bf16 out ----
template <int K>
__global__ __launch_bounds__(256) void mfma_gemm_kernel(const ushort* __restrict__ A,
                                                        const float* __restrict__ W,
                                                        const float* __restrict__ bias,
                                                        ushort* __restrict__ C, int M) {
    constexpr int LDW = K + 8;
    __shared__ ushort Ws[64 * LDW];
    const int tid = threadIdx.x;
    const int bm = blockIdx.x * 128;
    const int bn = blockIdx.y * 64;

    constexpr int CPR = K / 4;
    for (int idx = tid; idx < 64 * CPR; idx += 256) {
        int r = idx / CPR, c = idx % CPR;
        float4 v = *(const float4*)(W + (size_t)(bn + r) * K + c * 4);
        ushort4 o;
        o.x = f2bf(v.x); o.y = f2bf(v.y); o.z = f2bf(v.z); o.w = f2bf(v.w);
        *(ushort4*)(&Ws[r * LDW + c * 4]) = o;
    }
    __syncthreads();

    const int wave = tid >> 6;
    const int lane = tid & 63;
    const int lrow = lane & 15;
    const int lq   = lane >> 4;
    const int m0 = bm + wave * 32;

    f32x4 acc[2][4] = {};
    const int r0 = min(m0 + lrow, M - 1);
    const int r1 = min(m0 + 16 + lrow, M - 1);

    for (int k0 = 0; k0 < K; k0 += 32) {
        const int kk = k0 + lq * 8;
        short8 a0 = *(const short8*)(A + (size_t)r0 * K + kk);
        short8 a1 = *(const short8*)(A + (size_t)r1 * K + kk);
        short8 b[4];
#pragma unroll
        for (int j = 0; j < 4; j++)
            b[j] = *(const short8*)(&Ws[(j * 16 + lrow) * LDW + kk]);
#pragma unroll
        for (int j = 0; j < 4; j++) {
            acc[0][j] = __builtin_amdgcn_mfma_f32_16x16x32_bf16(a0, b[j], acc[0][j], 0, 0, 0);
            acc[1][j] = __builtin_amdgcn_mfma_f32_16x16x32_bf16(a1, b[j], acc[1][j], 0, 0, 0);
        }
    }

#pragma unroll
    for (int sub = 0; sub < 2; sub++) {
#pragma unroll
        for (int j = 0; j < 4; j++) {
            const int gn = bn + j * 16 + lrow;
            const float bv = bias[gn];
#pragma unroll
            for (int i = 0; i < 4; i++) {
                const int gm = m0 + sub * 16 + lq * 4 + i;
                if (gm < M) {
                    float v = acc[sub][j][i] + bv;
                    v = fmaxf(v, 0.0f);
                    C[(size_t)gm * HIDC + gn] = f2bf(v);
                }
            }
        }
    }
}

__device__ __forceinline__ int lower_bound_batch(const int* __restrict__ batch, int val) {
    int lo = 0, hi = NN;
    while (lo < hi) {
        int mid = (lo + hi) >> 1;
        if (batch[mid] < val) lo = mid + 1;
        else hi = mid;
    }
    return lo;
}

// ---- segmented mean-pool stage 1: partial sums over bf16 h ----
__global__ __launch_bounds__(256) void pool_partial_kernel(const ushort* __restrict__ h,
                                                           const int* __restrict__ batch,
                                                           float* __restrict__ partials) {
    const int g = blockIdx.x;
    const int p = blockIdx.y;
    const int c = threadIdx.x;
    const int lo = lower_bound_batch(batch, g);
    const int hi = lower_bound_batch(batch, g + 1);
    const int cnt = hi - lo;
    const int chunk = (cnt + PP - 1) / PP;
    const int n0 = lo + p * chunk;
    const int n1 = min(hi, n0 + chunk);
    float sum = 0.0f;
    for (int n = n0; n < n1; n++) sum += bf2f(h[(size_t)n * HIDC + c]);
    partials[((size_t)g * PP + p) * HIDC + c] = sum;
}

// ---- stage 2: reduce partials, mean, head linear (fp32) ----
__global__ __launch_bounds__(256) void head_kernel(const float* __restrict__ partials,
                                                   const int* __restrict__ batch,
                                                   const float* __restrict__ Wl,
                                                   const float* __restrict__ bl,
                                                   float* __restrict__ out) {
    __shared__ float s[HIDC];
    const int g = blockIdx.x;
    const int c = threadIdx.x;
    const int lo = lower_bound_batch(batch, g);
    const int hi = lower_bound_batch(batch, g + 1);
    const float inv = 1.0f / fmaxf((float)(hi - lo), 1.0f);
    float sum = 0.0f;
#pragma unroll
    for (int p = 0; p < PP; p++) sum += partials[((size_t)g * PP + p) * HIDC + c];
    s[c] = sum * inv;
    __syncthreads();
    if (c < OUTC) {
        float acc = bl[c];
        for (int k = 0; k < HIDC; k++) acc += s[k] * Wl[(size_t)c * HIDC + k];
        out[(size_t)g * OUTC + c] = acc;
    }
}

extern "C" void kernel_launch(void* const* d_in, const int* in_sizes, int n_in,
                              void* d_out, int out_size, void* d_ws, size_t ws_size,
                              hipStream_t stream) {
    const float* x     = (const float*)d_in[0];
    const int*   ei    = (const int*)d_in[1];
    const int*   batch = (const int*)d_in[2];
    const float* ew    = (const float*)d_in[3];
    const float* W1    = (const float*)d_in[4];
    const float* b1    = (const float*)d_in[5];
    const float* W2    = (const float*)d_in[6];
    const float* b2    = (const float*)d_in[7];
    const float* W3    = (const float*)d_in[8];
    const float* b3    = (const float*)d_in[9];
    const float* Wl    = (const float*)d_in[10];
    const float* bl    = (const float*)d_in[11];

    // ---- workspace layout ----
    char* p = (char*)d_ws;
    ushort* xb     = (ushort*)p; p += (size_t)NN * INC * 2;
    ushort* agg128 = (ushort*)p; p += (size_t)NN * INC * 2;
    ushort* agg256 = (ushort*)p; p += (size_t)NN * HIDC * 2;
    ushort* h      = (ushort*)p; p += (size_t)NN * HIDC * 2;
    uint*   erec   = (uint*)p;   p += (size_t)NE * 4;
    float*  partials = (float*)p; p += (size_t)NG * PP * HIDC * 4;
    int*    hist_b = (int*)p;    p += (size_t)HB * NN * 4;
    int*    row_start = (int*)p; p += 40016;
    int*    cur    = (int*)p;    p += (size_t)NN * 4;

    // ---- CSR build (per call) ----
    hist_kernel<<<HB, 1024, 0, stream>>>(ei, hist_b);
    scan_kernel<<<1, 1024, 0, stream>>>(hist_b, row_start, cur);
    build_kernel<<<(NE + 255) / 256, 256, 0, stream>>>(ei, ew, cur, erec);

    // ---- x -> bf16 ----
    f2bf_kernel<<<(NN * INC / 4 + 255) / 256, 256, 0, stream>>>(x, xb, NN * INC / 4);

    const int gather_grid = (NN + 3) / 4;
    dim3 gemm_grid((NN + 127) / 128, HIDC / 64);

    // ---- layer 1 (K=128) ----
    gather_bf16_kernel<INC><<<gather_grid, 256, 0, stream>>>(row_start, erec, xb, agg128);
    mfma_gemm_kernel<INC><<<gemm_grid, 256, 0, stream>>>(agg128, W1, b1, h, NN);

    // ---- layer 2 (K=256) ----
    gather_bf16_kernel<HIDC><<<gather_grid, 256, 0, stream>>>(row_start, erec, h, agg256);
    mfma_gemm_kernel<HIDC><<<gemm_grid, 256, 0, stream>>>(agg256, W2, b2, h, NN);

    // ---- layer 3 (K=256) ----
    gather_bf16_kernel<HIDC><<<gather_grid, 256, 0, stream>>>(row_start, erec, h, agg256);
    mfma_gemm_kernel<HIDC><<<gemm_grid, 256, 0, stream>>>(agg256, W3, b3, h, NN);

    // ---- global mean pool + head ----
    pool_partial_kernel<<<dim3(NG, PP), 256, 0, stream>>>(h, batch, partials);
    head_kernel<<<NG, 256, 0, stream>>>(partials, batch, Wl, bl, (float*)d_out);
}

// Round 8
// 283.182 us; speedup vs baseline: 1.4531x; 1.4531x over previous
//
#include <hip/hip_runtime.h>
#include <hip/hip_fp16.h>

namespace {
constexpr int NN   = 10000;   // nodes
constexpr int NE   = 640000;  // edges
constexpr int INC  = 128;     // input channels
constexpr int HIDC = 256;     // hidden channels
constexpr int OUTC = 10;      // output channels
constexpr int NG   = 64;      // graphs
constexpr int PP   = 8;       // pooling partials per graph
constexpr int HB   = 64;      // histogram blocks
}

typedef __attribute__((ext_vector_type(8))) short short8;
typedef __attribute__((ext_vector_type(4))) float f32x4;

__device__ __forceinline__ ushort f2bf(float f) {
    uint u = __float_as_uint(f);
    uint r = u + 0x7FFFu + ((u >> 16) & 1u);   // RNE
    return (ushort)(r >> 16);
}
__device__ __forceinline__ float bf2f(ushort u) {
    return __uint_as_float(((uint)u) << 16);
}
__device__ __forceinline__ float rec_w(uint rec) {
    return __half2float(__ushort_as_half((ushort)(rec & 0xFFFFu)));
}

// fp32 -> bf16, 4 elements/thread
__global__ __launch_bounds__(256) void f2bf_kernel(const float* __restrict__ in,
                                                   ushort* __restrict__ out, int n4) {
    int i = blockIdx.x * blockDim.x + threadIdx.x;
    if (i >= n4) return;
    float4 v = ((const float4*)in)[i];
    ushort4 o;
    o.x = f2bf(v.x); o.y = f2bf(v.y); o.z = f2bf(v.z); o.w = f2bf(v.w);
    ((ushort4*)out)[i] = o;
}

// ---- CSR build step 1: LDS-privatized histogram by dst ----
__global__ __launch_bounds__(1024) void hist_kernel(const int* __restrict__ ei,
                                                    int* __restrict__ hist_b) {
    __shared__ int h[NN];
    const int t = threadIdx.x;
    const int b = blockIdx.x;
    for (int i = t; i < NN; i += 1024) h[i] = 0;
    __syncthreads();
    constexpr int CHUNK = NE / HB;  // 10000
    const int base = NE + b * CHUNK;  // dst row of edge_index
    for (int i = t; i < CHUNK; i += 1024)
        atomicAdd(&h[ei[base + i]], 1);
    __syncthreads();
    for (int i = t; i < NN; i += 1024) hist_b[(size_t)b * NN + i] = h[i];
}

// ---- step 2a: grid-parallel fold of HB partial hists -> deg ----
__global__ __launch_bounds__(256) void fold_kernel(const int* __restrict__ hist_b,
                                                   int* __restrict__ deg) {
    int i = blockIdx.x * blockDim.x + threadIdx.x;
    if (i >= NN) return;
    int s = 0;
#pragma unroll 8
    for (int b = 0; b < HB; b++) s += hist_b[(size_t)b * NN + i];
    deg[i] = s;
}

// ---- step 2b: single-block exclusive scan over deg -> row_start, cur ----
__global__ __launch_bounds__(1024) void scan_kernel(const int* __restrict__ deg,
                                                    int* __restrict__ row_start,
                                                    int* __restrict__ cur) {
    __shared__ int part[1024];
    const int t = threadIdx.x;
    constexpr int C = (NN + 1023) / 1024;  // 10
    const int base = t * C;
    int d[C];
#pragma unroll
    for (int i = 0; i < C; i++) {
        int idx = base + i;
        d[i] = (idx < NN) ? deg[idx] : 0;
    }
    int sum = 0;
#pragma unroll
    for (int i = 0; i < C; i++) sum += d[i];
    part[t] = sum;
    __syncthreads();
    for (int off = 1; off < 1024; off <<= 1) {
        int v = (t >= off) ? part[t - off] : 0;
        __syncthreads();
        part[t] += v;
        __syncthreads();
    }
    int run = (t == 0) ? 0 : part[t - 1];
#pragma unroll
    for (int i = 0; i < C; i++) {
        int idx = base + i;
        if (idx < NN) {
            row_start[idx] = run;
            cur[idx] = run;
            run += d[i];
        }
    }
    if (t == 1023) row_start[NN] = run;
}

// ---- step 3: bucket-scatter edges into CSR order: one packed 4B record ----
__global__ __launch_bounds__(256) void build_kernel(const int* __restrict__ ei,
                                                    const float* __restrict__ ew,
                                                    int* __restrict__ cur,
                                                    uint* __restrict__ erec) {
    int e = blockIdx.x * blockDim.x + threadIdx.x;
    if (e >= NE) return;
    int d = ei[NE + e];
    int pos = atomicAdd(&cur[d], 1);
    ushort hw = __half_as_ushort(__float2half(ew[e]));
    erec[pos] = ((uint)ei[e] << 16) | (uint)hw;
}

// ---- aggregation via CSR gather (bf16 in/out, fp32 accumulate) ----
// out[n] = x[n] + sum_e w_e * x[src_e]; one wave per node, 12-edge batches.
template <int F>
__global__ __launch_bounds__(256) void gather_bf16_kernel(const int* __restrict__ row_start,
                                                          const uint* __restrict__ erec,
                                                          const ushort* __restrict__ x,
                                                          ushort* __restrict__ out) {
    constexpr int VEC = F / 64;  // bf16 per lane: 2 (F=128) or 4 (F=256)
    constexpr int U = 12;
    const int n = blockIdx.x * 4 + (threadIdx.x >> 6);
    const int lane = threadIdx.x & 63;
    if (n >= NN) return;
    const int beg = row_start[n];
    const int end = row_start[n + 1];
    const size_t loff = (size_t)lane * VEC;

    float acc[VEC];
    {
        ushort v[VEC];
        if (VEC == 4) *(ushort4*)v = *(const ushort4*)(x + (size_t)n * F + loff);
        else          *(ushort2*)v = *(const ushort2*)(x + (size_t)n * F + loff);
#pragma unroll
        for (int i = 0; i < VEC; i++) acc[i] = bf2f(v[i]);
    }

    int e = beg;
    for (; e + U <= end; e += U) {
        uint rec[U];
#pragma unroll
        for (int u = 0; u < U; u++) rec[u] = erec[e + u];
        ushort v[U][VEC];
#pragma unroll
        for (int u = 0; u < U; u++) {
            const ushort* r = x + (size_t)(rec[u] >> 16) * F + loff;
            if (VEC == 4) *(ushort4*)v[u] = *(const ushort4*)r;
            else          *(ushort2*)v[u] = *(const ushort2*)r;
        }
#pragma unroll
        for (int u = 0; u < U; u++) {
            const float w = rec_w(rec[u]);
#pragma unroll
            for (int i = 0; i < VEC; i++) acc[i] += w * bf2f(v[u][i]);
        }
    }
    for (; e < end; e++) {
        uint rec = erec[e];
        const float w = rec_w(rec);
        ushort v[VEC];
        const ushort* r = x + (size_t)(rec >> 16) * F + loff;
        if (VEC == 4) *(ushort4*)v = *(const ushort4*)r;
        else          *(ushort2*)v = *(const ushort2*)r;
#pragma unroll
        for (int i = 0; i < VEC; i++) acc[i] += w * bf2f(v[i]);
    }

    ushort o[VEC];
#pragma unroll
    for (int i = 0; i < VEC; i++) o[i] = f2bf(acc[i]);
    if (VEC == 4) *(ushort4*)(out + (size_t)n * F + loff) = *(ushort4*)o;
    else          *(ushort2*)(out + (size_t)n * F + loff) = *(ushort2*)o;
}

// ---- MFMA bf16 GEMM: C[M,256] = relu(A[M,K] @ W[256,K]^T + bias), bf16 out ----
template <int K>
__global__ __launch_bounds__(256) void mfma_gemm_kernel(const ushort* __restrict__ A,
                                                        const float* __restrict__ W,
                                                        const float* __restrict__ bias,
                                                        ushort* __restrict__ C, int M) {
    constexpr int LDW = K + 8;
    __shared__ ushort Ws[64 * LDW];
    const int tid = threadIdx.x;
    const int bm = blockIdx.x * 128;
    const int bn = blockIdx.y * 64;

    constexpr int CPR = K / 4;
    for (int idx = tid; idx < 64 * CPR; idx += 256) {
        int r = idx / CPR, c = idx % CPR;
        float4 v = *(const float4*)(W + (size_t)(bn + r) * K + c * 4);
        ushort4 o;
        o.x = f2bf(v.x); o.y = f2bf(v.y); o.z = f2bf(v.z); o.w = f2bf(v.w);
        *(ushort4*)(&Ws[r * LDW + c * 4]) = o;
    }
    __syncthreads();

    const int wave = tid >> 6;
    const int lane = tid & 63;
    const int lrow = lane & 15;
    const int lq   = lane >> 4;
    const int m0 = bm + wave * 32;

    f32x4 acc[2][4] = {};
    const int r0 = min(m0 + lrow, M - 1);
    const int r1 = min(m0 + 16 + lrow, M - 1);

    for (int k0 = 0; k0 < K; k0 += 32) {
        const int kk = k0 + lq * 8;
        short8 a0 = *(const short8*)(A + (size_t)r0 * K + kk);
        short8 a1 = *(const short8*)(A + (size_t)r1 * K + kk);
        short8 b[4];
#pragma unroll
        for (int j = 0; j < 4; j++)
            b[j] = *(const short8*)(&Ws[(j * 16 + lrow) * LDW + kk]);
#pragma unroll
        for (int j = 0; j < 4; j++) {
            acc[0][j] = __builtin_amdgcn_mfma_f32_16x16x32_bf16(a0, b[j], acc[0][j], 0, 0, 0);
            acc[1][j] = __builtin_amdgcn_mfma_f32_16x16x32_bf16(a1, b[j], acc[1][j], 0, 0, 0);
        }
    }

#pragma unroll
    for (int sub = 0; sub < 2; sub++) {
#pragma unroll
        for (int j = 0; j < 4; j++) {
            const int gn = bn + j * 16 + lrow;
            const float bv = bias[gn];
#pragma unroll
            for (int i = 0; i < 4; i++) {
                const int gm = m0 + sub * 16 + lq * 4 + i;
                if (gm < M) {
                    float v = acc[sub][j][i] + bv;
                    v = fmaxf(v, 0.0f);
                    C[(size_t)gm * HIDC + gn] = f2bf(v);
                }
            }
        }
    }
}

__device__ __forceinline__ int lower_bound_batch(const int* __restrict__ batch, int val) {
    int lo = 0, hi = NN;
    while (lo < hi) {
        int mid = (lo + hi) >> 1;
        if (batch[mid] < val) lo = mid + 1;
        else hi = mid;
    }
    return lo;
}

// ---- segmented mean-pool stage 1: partial sums over bf16 h ----
__global__ __launch_bounds__(256) void pool_partial_kernel(const ushort* __restrict__ h,
                                                           const int* __restrict__ batch,
                                                           float* __restrict__ partials) {
    const int g = blockIdx.x;
    const int p = blockIdx.y;
    const int c = threadIdx.x;
    const int lo = lower_bound_batch(batch, g);
    const int hi = lower_bound_batch(batch, g + 1);
    const int cnt = hi - lo;
    const int chunk = (cnt + PP - 1) / PP;
    const int n0 = lo + p * chunk;
    const int n1 = min(hi, n0 + chunk);
    float sum = 0.0f;
    for (int n = n0; n < n1; n++) sum += bf2f(h[(size_t)n * HIDC + c]);
    partials[((size_t)g * PP + p) * HIDC + c] = sum;
}

// ---- stage 2: reduce partials, mean, head linear (fp32) ----
__global__ __launch_bounds__(256) void head_kernel(const float* __restrict__ partials,
                                                   const int* __restrict__ batch,
                                                   const float* __restrict__ Wl,
                                                   const float* __restrict__ bl,
                                                   float* __restrict__ out) {
    __shared__ float s[HIDC];
    const int g = blockIdx.x;
    const int c = threadIdx.x;
    const int lo = lower_bound_batch(batch, g);
    const int hi = lower_bound_batch(batch, g + 1);
    const float inv = 1.0f / fmaxf((float)(hi - lo), 1.0f);
    float sum = 0.0f;
#pragma unroll
    for (int p = 0; p < PP; p++) sum += partials[((size_t)g * PP + p) * HIDC + c];
    s[c] = sum * inv;
    __syncthreads();
    if (c < OUTC) {
        float acc = bl[c];
        for (int k = 0; k < HIDC; k++) acc += s[k] * Wl[(size_t)c * HIDC + k];
        out[(size_t)g * OUTC + c] = acc;
    }
}

extern "C" void kernel_launch(void* const* d_in, const int* in_sizes, int n_in,
                              void* d_out, int out_size, void* d_ws, size_t ws_size,
                              hipStream_t stream) {
    const float* x     = (const float*)d_in[0];
    const int*   ei    = (const int*)d_in[1];
    const int*   batch = (const int*)d_in[2];
    const float* ew    = (const float*)d_in[3];
    const float* W1    = (const float*)d_in[4];
    const float* b1    = (const float*)d_in[5];
    const float* W2    = (const float*)d_in[6];
    const float* b2    = (const float*)d_in[7];
    const float* W3    = (const float*)d_in[8];
    const float* b3    = (const float*)d_in[9];
    const float* Wl    = (const float*)d_in[10];
    const float* bl    = (const float*)d_in[11];

    // ---- workspace layout ----
    char* p = (char*)d_ws;
    ushort* xb     = (ushort*)p; p += (size_t)NN * INC * 2;
    ushort* agg128 = (ushort*)p; p += (size_t)NN * INC * 2;
    ushort* agg256 = (ushort*)p; p += (size_t)NN * HIDC * 2;
    ushort* h      = (ushort*)p; p += (size_t)NN * HIDC * 2;
    uint*   erec   = (uint*)p;   p += (size_t)NE * 4;
    float*  partials = (float*)p; p += (size_t)NG * PP * HIDC * 4;
    int*    hist_b = (int*)p;    p += (size_t)HB * NN * 4;
    int*    deg    = (int*)p;    p += (size_t)NN * 4;
    int*    row_start = (int*)p; p += 40016;
    int*    cur    = (int*)p;    p += (size_t)NN * 4;

    // ---- CSR build (per call) ----
    hist_kernel<<<HB, 1024, 0, stream>>>(ei, hist_b);
    fold_kernel<<<(NN + 255) / 256, 256, 0, stream>>>(hist_b, deg);
    scan_kernel<<<1, 1024, 0, stream>>>(deg, row_start, cur);
    build_kernel<<<(NE + 255) / 256, 256, 0, stream>>>(ei, ew, cur, erec);

    // ---- x -> bf16 ----
    f2bf_kernel<<<(NN * INC / 4 + 255) / 256, 256, 0, stream>>>(x, xb, NN * INC / 4);

    const int gather_grid = (NN + 3) / 4;
    dim3 gemm_grid((NN + 127) / 128, HIDC / 64);

    // ---- layer 1 (K=128) ----
    gather_bf16_kernel<INC><<<gather_grid, 256, 0, stream>>>(row_start, erec, xb, agg128);
    mfma_gemm_kernel<INC><<<gemm_grid, 256, 0, stream>>>(agg128, W1, b1, h, NN);

    // ---- layer 2 (K=256) ----
    gather_bf16_kernel<HIDC><<<gather_grid, 256, 0, stream>>>(row_start, erec, h, agg256);
    mfma_gemm_kernel<HIDC><<<gemm_grid, 256, 0, stream>>>(agg256, W2, b2, h, NN);

    // ---- layer 3 (K=256) ----
    gather_bf16_kernel<HIDC><<<gather_grid, 256, 0, stream>>>(row_start, erec, h, agg256);
    mfma_gemm_kernel<HIDC><<<gemm_grid, 256, 0, stream>>>(agg256, W3, b3, h, NN);

    // ---- global mean pool + head ----
    pool_partial_kernel<<<dim3(NG, PP), 256, 0, stream>>>(h, batch, partials);
    head_kernel<<<NG, 256, 0, stream>>>(partials, batch, Wl, bl, (float*)d_out);
}

// Round 9
// 277.852 us; speedup vs baseline: 1.4810x; 1.0192x over previous
//
#include <hip/hip_runtime.h>
#include <hip/hip_fp16.h>

namespace {
constexpr int NN   = 10000;   // nodes
constexpr int NE   = 640000;  // edges
constexpr int INC  = 128;     // input channels
constexpr int HIDC = 256;     // hidden channels
constexpr int OUTC = 10;      // output channels
constexpr int NG   = 64;      // graphs
constexpr int PP   = 8;       // pooling partials per graph

// radix-partition CSR build
constexpr int NB     = 157;       // dst buckets of 64 nodes (bucket = dst>>6)
constexpr int G1     = 64;        // partition blocks
constexpr int CHUNK1 = NE / G1;   // 10000 edges per partition block
constexpr int CAPB   = 128;       // per (block,bucket) fragment capacity (mean 64, ~8 sigma margin)
}

typedef __attribute__((ext_vector_type(8))) short short8;
typedef __attribute__((ext_vector_type(4))) float f32x4;

__device__ __forceinline__ ushort f2bf(float f) {
    uint u = __float_as_uint(f);
    uint r = u + 0x7FFFu + ((u >> 16) & 1u);   // RNE
    return (ushort)(r >> 16);
}
__device__ __forceinline__ float bf2f(ushort u) {
    return __uint_as_float(((uint)u) << 16);
}
__device__ __forceinline__ float rec_w(uint rec) {
    return __half2float(__ushort_as_half((ushort)(rec & 0xFFFFu)));
}

// fp32 -> bf16, 4 elements/thread
__global__ __launch_bounds__(256) void f2bf_kernel(const float* __restrict__ in,
                                                   ushort* __restrict__ out, int n4) {
    int i = blockIdx.x * blockDim.x + threadIdx.x;
    if (i >= n4) return;
    float4 v = ((const float4*)in)[i];
    ushort4 o;
    o.x = f2bf(v.x); o.y = f2bf(v.y); o.z = f2bf(v.z); o.w = f2bf(v.w);
    ((ushort4*)out)[i] = o;
}

// ---- CSR pass 1: partition edges into block-private per-bucket fragments ----
// Record: {x = (src<<16)|half(w), y = dst}. Writes land in this block's own
// 128-KB region -> lines owned by one CU -> dense writeback. No global atomics.
__global__ __launch_bounds__(256) void partition_kernel(const int* __restrict__ ei,
                                                        const float* __restrict__ ew,
                                                        uint2* __restrict__ stag,
                                                        int* __restrict__ cnts) {
    __shared__ int lcnt[NB];
    const int t = threadIdx.x, g = blockIdx.x;
    for (int i = t; i < NB; i += 256) lcnt[i] = 0;
    __syncthreads();
    const int base = g * CHUNK1;
    for (int i = t; i < CHUNK1; i += 256) {
        const int e = base + i;
        const int dst = ei[NE + e];
        const int src = ei[e];
        const ushort hw = __half_as_ushort(__float2half(ew[e]));
        const int bk = dst >> 6;
        const int idx = atomicAdd(&lcnt[bk], 1);
        if (idx < CAPB)
            stag[((size_t)g * NB + bk) * CAPB + idx] =
                make_uint2(((uint)src << 16) | (uint)hw, (uint)dst);
    }
    __syncthreads();
    for (int i = t; i < NB; i += 256) cnts[g * NB + i] = min(lcnt[i], CAPB);
}

// ---- CSR pass 2a: bucket totals + exclusive scan -> bucket_start ----
__global__ __launch_bounds__(256) void bucketscan_kernel(const int* __restrict__ cnts,
                                                         int* __restrict__ bucket_start,
                                                         int* __restrict__ row_start) {
    __shared__ int part[256];
    const int t = threadIdx.x;
    int s = 0;
    if (t < NB)
        for (int g = 0; g < G1; g++) s += cnts[g * NB + t];
    part[t] = s;
    __syncthreads();
    for (int off = 1; off < 256; off <<= 1) {
        int v = (t >= off) ? part[t - off] : 0;
        __syncthreads();
        part[t] += v;
        __syncthreads();
    }
    if (t < NB) bucket_start[t] = part[t] - s;
    if (t == 0) {
        bucket_start[NB] = part[255];
        row_start[NN] = part[255];
    }
}

// ---- CSR pass 2b: per-bucket counting sort -> row_start + final packed erec ----
// One block per bucket; all erec writes land in this bucket's contiguous
// ~16-KB segment, written by a single CU -> dense lines.
__global__ __launch_bounds__(256) void place_kernel(const uint2* __restrict__ stag,
                                                    const int* __restrict__ cnts,
                                                    const int* __restrict__ bucket_start,
                                                    int* __restrict__ row_start,
                                                    uint* __restrict__ erec) {
    const int b = blockIdx.x;
    const int t = threadIdx.x;
    __shared__ int part[256];
    __shared__ int foff[G1 + 1];
    __shared__ int h[64];
    __shared__ int curl[64];

    // fragment offsets within this bucket (exclusive scan of cnts[:, b])
    const int c = (t < G1) ? cnts[t * NB + b] : 0;
    part[t] = c;
    __syncthreads();
    for (int off = 1; off < 256; off <<= 1) {
        int v = (t >= off) ? part[t - off] : 0;
        __syncthreads();
        part[t] += v;
        __syncthreads();
    }
    if (t < G1) foff[t] = part[t] - c;
    if (t == 0) foff[G1] = part[255];
    if (t < 64) h[t] = 0;
    __syncthreads();
    const int Rb = foff[G1];

    // histogram over dst_low
    for (int r = t; r < Rb; r += 256) {
        int lo = 0, hi = G1;
        while (hi - lo > 1) { int mid = (lo + hi) >> 1; if (foff[mid] <= r) lo = mid; else hi = mid; }
        uint2 rec = stag[((size_t)lo * NB + b) * CAPB + (r - foff[lo])];
        atomicAdd(&h[rec.y & 63], 1);
    }
    __syncthreads();

    // scan h -> node offsets; emit row_start for this bucket's nodes
    const int hv = (t < 64) ? h[t] : 0;
    part[t] = hv;
    __syncthreads();
    for (int off = 1; off < 256; off <<= 1) {
        int v = (t >= off) ? part[t - off] : 0;
        __syncthreads();
        part[t] += v;
        __syncthreads();
    }
    const int bs = bucket_start[b];
    if (t < 64) {
        const int excl = part[t] - hv;
        const int node = b * 64 + t;
        if (node < NN) row_start[node] = bs + excl;
        curl[t] = excl;
    }
    __syncthreads();

    // place records
    for (int r = t; r < Rb; r += 256) {
        int lo = 0, hi = G1;
        while (hi - lo > 1) { int mid = (lo + hi) >> 1; if (foff[mid] <= r) lo = mid; else hi = mid; }
        uint2 rec = stag[((size_t)lo * NB + b) * CAPB + (r - foff[lo])];
        const int pos = bs + atomicAdd(&curl[rec.y & 63], 1);
        erec[pos] = rec.x;
    }
}

// ---- aggregation via CSR gather (bf16 in/out, fp32 accumulate) ----
template <int F>
__global__ __launch_bounds__(256) void gather_bf16_kernel(const int* __restrict__ row_start,
                                                          const uint* __restrict__ erec,
                                                          const ushort* __restrict__ x,
                                                          ushort* __restrict__ out) {
    constexpr int VEC = F / 64;
    constexpr int U = 12;
    const int n = blockIdx.x * 4 + (threadIdx.x >> 6);
    const int lane = threadIdx.x & 63;
    if (n >= NN) return;
    const int beg = row_start[n];
    const int end = row_start[n + 1];
    const size_t loff = (size_t)lane * VEC;

    float acc[VEC];
    {
        ushort v[VEC];
        if (VEC == 4) *(ushort4*)v = *(const ushort4*)(x + (size_t)n * F + loff);
        else          *(ushort2*)v = *(const ushort2*)(x + (size_t)n * F + loff);
#pragma unroll
        for (int i = 0; i < VEC; i++) acc[i] = bf2f(v[i]);
    }

    int e = beg;
    for (; e + U <= end; e += U) {
        uint rec[U];
#pragma unroll
        for (int u = 0; u < U; u++) rec[u] = erec[e + u];
        ushort v[U][VEC];
#pragma unroll
        for (int u = 0; u < U; u++) {
            const ushort* r = x + (size_t)(rec[u] >> 16) * F + loff;
            if (VEC == 4) *(ushort4*)v[u] = *(const ushort4*)r;
            else          *(ushort2*)v[u] = *(const ushort2*)r;
        }
#pragma unroll
        for (int u = 0; u < U; u++) {
            const float w = rec_w(rec[u]);
#pragma unroll
            for (int i = 0; i < VEC; i++) acc[i] += w * bf2f(v[u][i]);
        }
    }
    for (; e < end; e++) {
        uint rec = erec[e];
        const float w = rec_w(rec);
        ushort v[VEC];
        const ushort* r = x + (size_t)(rec >> 16) * F + loff;
        if (VEC == 4) *(ushort4*)v = *(const ushort4*)r;
        else          *(ushort2*)v = *(const ushort2*)r;
#pragma unroll
        for (int i = 0; i < VEC; i++) acc[i] += w * bf2f(v[i]);
    }

    ushort o[VEC];
#pragma unroll
    for (int i = 0; i < VEC; i++) o[i] = f2bf(acc[i]);
    if (VEC == 4) *(ushort4*)(out + (size_t)n * F + loff) = *(ushort4*)o;
    else          *(ushort2*)(out + (size_t)n * F + loff) = *(ushort2*)o;
}

// ---- MFMA bf16 GEMM: C[M,256] = relu(A[M,K] @ W[256,K]^T + bias), bf16 out ----
template <int K>
__global__ __launch_bounds__(256) void mfma_gemm_kernel(const ushort* __restrict__ A,
                                                        const float* __restrict__ W,
                                                        const float* __restrict__ bias,
                                                        ushort* __restrict__ C, int M) {
    constexpr int LDW = K + 8;
    __shared__ ushort Ws[64 * LDW];
    const int tid = threadIdx.x;
    const int bm = blockIdx.x * 128;
    const int bn = blockIdx.y * 64;

    constexpr int CPR = K / 4;
    for (int idx = tid; idx < 64 * CPR; idx += 256) {
        int r = idx / CPR, c = idx % CPR;
        float4 v = *(const float4*)(W + (size_t)(bn + r) * K + c * 4);
        ushort4 o;
        o.x = f2bf(v.x); o.y = f2bf(v.y); o.z = f2bf(v.z); o.w = f2bf(v.w);
        *(ushort4*)(&Ws[r * LDW + c * 4]) = o;
    }
    __syncthreads();

    const int wave = tid >> 6;
    const int lane = tid & 63;
    const int lrow = lane & 15;
    const int lq   = lane >> 4;
    const int m0 = bm + wave * 32;

    f32x4 acc[2][4] = {};
    const int r0 = min(m0 + lrow, M - 1);
    const int r1 = min(m0 + 16 + lrow, M - 1);

    for (int k0 = 0; k0 < K; k0 += 32) {
        const int kk = k0 + lq * 8;
        short8 a0 = *(const short8*)(A + (size_t)r0 * K + kk);
        short8 a1 = *(const short8*)(A + (size_t)r1 * K + kk);
        short8 b[4];
#pragma unroll
        for (int j = 0; j < 4; j++)
            b[j] = *(const short8*)(&Ws[(j * 16 + lrow) * LDW + kk]);
#pragma unroll
        for (int j = 0; j < 4; j++) {
            acc[0][j] = __builtin_amdgcn_mfma_f32_16x16x32_bf16(a0, b[j], acc[0][j], 0, 0, 0);
            acc[1][j] = __builtin_amdgcn_mfma_f32_16x16x32_bf16(a1, b[j], acc[1][j], 0, 0, 0);
        }
    }

#pragma unroll
    for (int sub = 0; sub < 2; sub++) {
#pragma unroll
        for (int j = 0; j < 4; j++) {
            const int gn = bn + j * 16 + lrow;
            const float bv = bias[gn];
#pragma unroll
            for (int i = 0; i < 4; i++) {
                const int gm = m0 + sub * 16 + lq * 4 + i;
                if (gm < M) {
                    float v = acc[sub][j][i] + bv;
                    v = fmaxf(v, 0.0f);
                    C[(size_t)gm * HIDC + gn] = f2bf(v);
                }
            }
        }
    }
}

__device__ __forceinline__ int lower_bound_batch(const int* __restrict__ batch, int val) {
    int lo = 0, hi = NN;
    while (lo < hi) {
        int mid = (lo + hi) >> 1;
        if (batch[mid] < val) lo = mid + 1;
        else hi = mid;
    }
    return lo;
}

// ---- segmented mean-pool stage 1: partial sums over bf16 h ----
__global__ __launch_bounds__(256) void pool_partial_kernel(const ushort* __restrict__ h,
                                                           const int* __restrict__ batch,
                                                           float* __restrict__ partials) {
    const int g = blockIdx.x;
    const int p = blockIdx.y;
    const int c = threadIdx.x;
    const int lo = lower_bound_batch(batch, g);
    const int hi = lower_bound_batch(batch, g + 1);
    const int cnt = hi - lo;
    const int chunk = (cnt + PP - 1) / PP;
    const int n0 = lo + p * chunk;
    const int n1 = min(hi, n0 + chunk);
    float sum = 0.0f;
    for (int n = n0; n < n1; n++) sum += bf2f(h[(size_t)n * HIDC + c]);
    partials[((size_t)g * PP + p) * HIDC + c] = sum;
}

// ---- stage 2: reduce partials, mean, head linear (fp32) ----
__global__ __launch_bounds__(256) void head_kernel(const float* __restrict__ partials,
                                                   const int* __restrict__ batch,
                                                   const float* __restrict__ Wl,
                                                   const float* __restrict__ bl,
                                                   float* __restrict__ out) {
    __shared__ float s[HIDC];
    const int g = blockIdx.x;
    const int c = threadIdx.x;
    const int lo = lower_bound_batch(batch, g);
    const int hi = lower_bound_batch(batch, g + 1);
    const float inv = 1.0f / fmaxf((float)(hi - lo), 1.0f);
    float sum = 0.0f;
#pragma unroll
    for (int p = 0; p < PP; p++) sum += partials[((size_t)g * PP + p) * HIDC + c];
    s[c] = sum * inv;
    __syncthreads();
    if (c < OUTC) {
        float acc = bl[c];
        for (int k = 0; k < HIDC; k++) acc += s[k] * Wl[(size_t)c * HIDC + k];
        out[(size_t)g * OUTC + c] = acc;
    }
}

extern "C" void kernel_launch(void* const* d_in, const int* in_sizes, int n_in,
                              void* d_out, int out_size, void* d_ws, size_t ws_size,
                              hipStream_t stream) {
    const float* x     = (const float*)d_in[0];
    const int*   ei    = (const int*)d_in[1];
    const int*   batch = (const int*)d_in[2];
    const float* ew    = (const float*)d_in[3];
    const float* W1    = (const float*)d_in[4];
    const float* b1    = (const float*)d_in[5];
    const float* W2    = (const float*)d_in[6];
    const float* b2    = (const float*)d_in[7];
    const float* W3    = (const float*)d_in[8];
    const float* b3    = (const float*)d_in[9];
    const float* Wl    = (const float*)d_in[10];
    const float* bl    = (const float*)d_in[11];

    // ---- workspace layout ----
    // staging region is dead after place_kernel; xb/agg128 (then agg256) alias it.
    char* p = (char*)d_ws;
    uint2* stag = (uint2*)p;                        // [G1][NB][CAPB] = ~10.3 MB
    ushort* xb     = (ushort*)p;                    //  2.56 MB (after place)
    ushort* agg128 = xb + (size_t)NN * INC;         //  2.56 MB
    ushort* agg256 = (ushort*)p;                    //  5.12 MB (after layer-1 gemm)
    p += (size_t)G1 * NB * CAPB * 8;
    ushort* h      = (ushort*)p; p += (size_t)NN * HIDC * 2;
    uint*   erec   = (uint*)p;   p += (size_t)NE * 4;
    float*  partials = (float*)p; p += (size_t)NG * PP * HIDC * 4;
    int*    cnts   = (int*)p;    p += (size_t)G1 * NB * 4;
    int*    bucket_start = (int*)p; p += (NB + 1) * 4 + 12;
    int*    row_start = (int*)p; p += 40016;

    // ---- CSR build: radix partition (per call) ----
    partition_kernel<<<G1, 256, 0, stream>>>(ei, ew, stag, cnts);
    bucketscan_kernel<<<1, 256, 0, stream>>>(cnts, bucket_start, row_start);
    place_kernel<<<NB, 256, 0, stream>>>(stag, cnts, bucket_start, row_start, erec);

    // ---- x -> bf16 (staging now dead; xb aliases it) ----
    f2bf_kernel<<<(NN * INC / 4 + 255) / 256, 256, 0, stream>>>(x, xb, NN * INC / 4);

    const int gather_grid = (NN + 3) / 4;
    dim3 gemm_grid((NN + 127) / 128, HIDC / 64);

    // ---- layer 1 (K=128) ----
    gather_bf16_kernel<INC><<<gather_grid, 256, 0, stream>>>(row_start, erec, xb, agg128);
    mfma_gemm_kernel<INC><<<gemm_grid, 256, 0, stream>>>(agg128, W1, b1, h, NN);

    // ---- layer 2 (K=256) ----
    gather_bf16_kernel<HIDC><<<gather_grid, 256, 0, stream>>>(row_start, erec, h, agg256);
    mfma_gemm_kernel<HIDC><<<gemm_grid, 256, 0, stream>>>(agg256, W2, b2, h, NN);

    // ---- layer 3 (K=256) ----
    gather_bf16_kernel<HIDC><<<gather_grid, 256, 0, stream>>>(row_start, erec, h, agg256);
    mfma_gemm_kernel<HIDC><<<gemm_grid, 256, 0, stream>>>(agg256, W3, b3, h, NN);

    // ---- global mean pool + head ----
    pool_partial_kernel<<<dim3(NG, PP), 256, 0, stream>>>(h, batch, partials);
    head_kernel<<<NG, 256, 0, stream>>>(partials, batch, Wl, bl, (float*)d_out);
}

// Round 10
// 261.351 us; speedup vs baseline: 1.5745x; 1.0631x over previous
//
#include <hip/hip_runtime.h>
#include <hip/hip_fp16.h>

namespace {
constexpr int NN   = 10000;   // nodes
constexpr int NE   = 640000;  // edges
constexpr int INC  = 128;     // input channels
constexpr int HIDC = 256;     // hidden channels
constexpr int OUTC = 10;      // output channels
constexpr int NG   = 64;      // graphs
constexpr int PP   = 8;       // pooling partials per graph

// radix-partition CSR build
constexpr int NB     = 157;       // dst buckets of 64 nodes (bucket = dst>>6)
constexpr int G1     = 256;       // partition blocks
constexpr int CHUNK1 = NE / G1;   // 2500 edges per partition block
constexpr int CAPB   = 64;        // per (block,bucket) fragment cap (mean 16, +12 sigma)
constexpr int LCAP   = 5120;      // place LDS record cache (bucket mean 4096, +16 sigma)
}

typedef __attribute__((ext_vector_type(8))) short short8;
typedef __attribute__((ext_vector_type(4))) float f32x4;

__device__ __forceinline__ ushort f2bf(float f) {
    uint u = __float_as_uint(f);
    uint r = u + 0x7FFFu + ((u >> 16) & 1u);   // RNE
    return (ushort)(r >> 16);
}
__device__ __forceinline__ float bf2f(ushort u) {
    return __uint_as_float(((uint)u) << 16);
}
__device__ __forceinline__ float rec_w(uint rec) {
    return __half2float(__ushort_as_half((ushort)(rec & 0xFFFFu)));
}

// ---- CSR pass 1: partition edges into block-private per-bucket fragments ----
// Record: {x = (src<<16)|half(w), y = dst}. Fused tail: x fp32 -> bf16.
__global__ __launch_bounds__(256) void partition_kernel(const int* __restrict__ ei,
                                                        const float* __restrict__ ew,
                                                        uint2* __restrict__ stag,
                                                        int* __restrict__ cnts,
                                                        int* __restrict__ cnts_T,
                                                        const float* __restrict__ x,
                                                        ushort* __restrict__ xb) {
    __shared__ int lcnt[NB];
    const int t = threadIdx.x, g = blockIdx.x;
    for (int i = t; i < NB; i += 256) lcnt[i] = 0;
    __syncthreads();
    const int base = g * CHUNK1;
    for (int i = t; i < CHUNK1; i += 256) {
        const int e = base + i;
        const int dst = ei[NE + e];
        const int src = ei[e];
        const ushort hw = __half_as_ushort(__float2half(ew[e]));
        const int bk = dst >> 6;
        const int idx = atomicAdd(&lcnt[bk], 1);
        if (idx < CAPB)
            stag[((size_t)g * NB + bk) * CAPB + idx] =
                make_uint2(((uint)src << 16) | (uint)hw, (uint)dst);
    }
    __syncthreads();
    for (int i = t; i < NB; i += 256) {
        const int c = min(lcnt[i], CAPB);
        cnts[g * NB + i] = c;          // g-major: coalesced, read by place
        cnts_T[i * G1 + g] = c;        // b-major: contiguous rows for bucketscan
    }
    // fused: x fp32 -> bf16 (independent of staging)
    const int total4 = NN * INC / 4;
    for (int i = g * 256 + t; i < total4; i += G1 * 256) {
        float4 v = ((const float4*)x)[i];
        ushort4 o;
        o.x = f2bf(v.x); o.y = f2bf(v.y); o.z = f2bf(v.z); o.w = f2bf(v.w);
        ((ushort4*)xb)[i] = o;
    }
}

// ---- CSR pass 2a: bucket totals (contiguous int4 reads) + exclusive scan ----
__global__ __launch_bounds__(256) void bucketscan_kernel(const int* __restrict__ cnts_T,
                                                         int* __restrict__ bucket_start,
                                                         int* __restrict__ row_start) {
    __shared__ int part[256];
    const int t = threadIdx.x;
    int s = 0;
    if (t < NB) {
        const int4* r = (const int4*)(cnts_T + (size_t)t * G1);
#pragma unroll 8
        for (int i = 0; i < G1 / 4; i++) {
            int4 v = r[i];
            s += v.x + v.y + v.z + v.w;
        }
    }
    part[t] = s;
    __syncthreads();
    for (int off = 1; off < 256; off <<= 1) {
        int v = (t >= off) ? part[t - off] : 0;
        __syncthreads();
        part[t] += v;
        __syncthreads();
    }
    if (t < NB) bucket_start[t] = part[t] - s;
    if (t == 0) {
        bucket_start[NB] = part[255];
        row_start[NN] = part[255];
    }
}

// ---- CSR pass 2b: per-bucket counting sort, records cached in LDS ----
// One block per bucket; single global read of the bucket's records.
__global__ __launch_bounds__(256) void place_kernel(const uint2* __restrict__ stag,
                                                    const int* __restrict__ cnts,
                                                    const int* __restrict__ bucket_start,
                                                    int* __restrict__ row_start,
                                                    uint* __restrict__ erec) {
    const int b = blockIdx.x;
    const int t = threadIdx.x;
    __shared__ int part[256];
    __shared__ int foff[G1 + 1];
    __shared__ int h[64];
    __shared__ int curl[64];
    __shared__ uint2 srec[LCAP];

    // fragment offsets within this bucket (exclusive scan of cnts[:, b])
    const int c = cnts[t * NB + b];
    part[t] = c;
    if (t < 64) h[t] = 0;
    __syncthreads();
    for (int off = 1; off < 256; off <<= 1) {
        int v = (t >= off) ? part[t - off] : 0;
        __syncthreads();
        part[t] += v;
        __syncthreads();
    }
    foff[t] = part[t] - c;
    if (t == 255) foff[G1] = part[255];
    __syncthreads();
    const int Rb = foff[G1];

    // single global pass: load records into LDS + histogram dst_low
    for (int r = t; r < Rb; r += 256) {
        int lo = 0, hi = G1;
        while (hi - lo > 1) { int mid = (lo + hi) >> 1; if (foff[mid] <= r) lo = mid; else hi = mid; }
        uint2 rec = stag[((size_t)lo * NB + b) * CAPB + (r - foff[lo])];
        if (r < LCAP) srec[r] = rec;
        atomicAdd(&h[rec.y & 63], 1);
    }
    __syncthreads();

    // scan h -> node offsets; emit row_start for this bucket's nodes
    const int hv = (t < 64) ? h[t] : 0;
    part[t] = hv;
    __syncthreads();
    for (int off = 1; off < 256; off <<= 1) {
        int v = (t >= off) ? part[t - off] : 0;
        __syncthreads();
        part[t] += v;
        __syncthreads();
    }
    const int bs = bucket_start[b];
    if (t < 64) {
        const int excl = part[t] - hv;
        const int node = b * 64 + t;
        if (node < NN) row_start[node] = bs + excl;
        curl[t] = excl;
    }
    __syncthreads();

    // place records (LDS-resident; global fallback for >LCAP overflow)
    for (int r = t; r < Rb; r += 256) {
        uint2 rec;
        if (r < LCAP) rec = srec[r];
        else {
            int lo = 0, hi = G1;
            while (hi - lo > 1) { int mid = (lo + hi) >> 1; if (foff[mid] <= r) lo = mid; else hi = mid; }
            rec = stag[((size_t)lo * NB + b) * CAPB + (r - foff[lo])];
        }
        const int pos = bs + atomicAdd(&curl[rec.y & 63], 1);
        erec[pos] = rec.x;
    }
}

// ---- aggregation via CSR gather (bf16 in/out, fp32 accumulate) ----
template <int F>
__global__ __launch_bounds__(256) void gather_bf16_kernel(const int* __restrict__ row_start,
                                                          const uint* __restrict__ erec,
                                                          const ushort* __restrict__ x,
                                                          ushort* __restrict__ out) {
    constexpr int VEC = F / 64;
    constexpr int U = 12;
    const int n = blockIdx.x * 4 + (threadIdx.x >> 6);
    const int lane = threadIdx.x & 63;
    if (n >= NN) return;
    const int beg = row_start[n];
    const int end = row_start[n + 1];
    const size_t loff = (size_t)lane * VEC;

    float acc[VEC];
    {
        ushort v[VEC];
        if (VEC == 4) *(ushort4*)v = *(const ushort4*)(x + (size_t)n * F + loff);
        else          *(ushort2*)v = *(const ushort2*)(x + (size_t)n * F + loff);
#pragma unroll
        for (int i = 0; i < VEC; i++) acc[i] = bf2f(v[i]);
    }

    int e = beg;
    for (; e + U <= end; e += U) {
        uint rec[U];
#pragma unroll
        for (int u = 0; u < U; u++) rec[u] = erec[e + u];
        ushort v[U][VEC];
#pragma unroll
        for (int u = 0; u < U; u++) {
            const ushort* r = x + (size_t)(rec[u] >> 16) * F + loff;
            if (VEC == 4) *(ushort4*)v[u] = *(const ushort4*)r;
            else          *(ushort2*)v[u] = *(const ushort2*)r;
        }
#pragma unroll
        for (int u = 0; u < U; u++) {
            const float w = rec_w(rec[u]);
#pragma unroll
            for (int i = 0; i < VEC; i++) acc[i] += w * bf2f(v[u][i]);
        }
    }
    for (; e < end; e++) {
        uint rec = erec[e];
        const float w = rec_w(rec);
        ushort v[VEC];
        const ushort* r = x + (size_t)(rec >> 16) * F + loff;
        if (VEC == 4) *(ushort4*)v = *(const ushort4*)r;
        else          *(ushort2*)v = *(const ushort2*)r;
#pragma unroll
        for (int i = 0; i < VEC; i++) acc[i] += w * bf2f(v[i]);
    }

    ushort o[VEC];
#pragma unroll
    for (int i = 0; i < VEC; i++) o[i] = f2bf(acc[i]);
    if (VEC == 4) *(ushort4*)(out + (size_t)n * F + loff) = *(ushort4*)o;
    else          *(ushort2*)(out + (size_t)n * F + loff) = *(ushort2*)o;
}

// ---- MFMA bf16 GEMM: C[M,256] = relu(A[M,K] @ W[256,K]^T + bias), bf16 out ----
template <int K>
__global__ __launch_bounds__(256) void mfma_gemm_kernel(const ushort* __restrict__ A,
                                                        const float* __restrict__ W,
                                                        const float* __restrict__ bias,
                                                        ushort* __restrict__ C, int M) {
    constexpr int LDW = K + 8;
    __shared__ ushort Ws[64 * LDW];
    const int tid = threadIdx.x;
    const int bm = blockIdx.x * 128;
    const int bn = blockIdx.y * 64;

    constexpr int CPR = K / 4;
    for (int idx = tid; idx < 64 * CPR; idx += 256) {
        int r = idx / CPR, c = idx % CPR;
        float4 v = *(const float4*)(W + (size_t)(bn + r) * K + c * 4);
        ushort4 o;
        o.x = f2bf(v.x); o.y = f2bf(v.y); o.z = f2bf(v.z); o.w = f2bf(v.w);
        *(ushort4*)(&Ws[r * LDW + c * 4]) = o;
    }
    __syncthreads();

    const int wave = tid >> 6;
    const int lane = tid & 63;
    const int lrow = lane & 15;
    const int lq   = lane >> 4;
    const int m0 = bm + wave * 32;

    f32x4 acc[2][4] = {};
    const int r0 = min(m0 + lrow, M - 1);
    const int r1 = min(m0 + 16 + lrow, M - 1);

    for (int k0 = 0; k0 < K; k0 += 32) {
        const int kk = k0 + lq * 8;
        short8 a0 = *(const short8*)(A + (size_t)r0 * K + kk);
        short8 a1 = *(const short8*)(A + (size_t)r1 * K + kk);
        short8 b[4];
#pragma unroll
        for (int j = 0; j < 4; j++)
            b[j] = *(const short8*)(&Ws[(j * 16 + lrow) * LDW + kk]);
#pragma unroll
        for (int j = 0; j < 4; j++) {
            acc[0][j] = __builtin_amdgcn_mfma_f32_16x16x32_bf16(a0, b[j], acc[0][j], 0, 0, 0);
            acc[1][j] = __builtin_amdgcn_mfma_f32_16x16x32_bf16(a1, b[j], acc[1][j], 0, 0, 0);
        }
    }

#pragma unroll
    for (int sub = 0; sub < 2; sub++) {
#pragma unroll
        for (int j = 0; j < 4; j++) {
            const int gn = bn + j * 16 + lrow;
            const float bv = bias[gn];
#pragma unroll
            for (int i = 0; i < 4; i++) {
                const int gm = m0 + sub * 16 + lq * 4 + i;
                if (gm < M) {
                    float v = acc[sub][j][i] + bv;
                    v = fmaxf(v, 0.0f);
                    C[(size_t)gm * HIDC + gn] = f2bf(v);
                }
            }
        }
    }
}

__device__ __forceinline__ int lower_bound_batch(const int* __restrict__ batch, int val) {
    int lo = 0, hi = NN;
    while (lo < hi) {
        int mid = (lo + hi) >> 1;
        if (batch[mid] < val) lo = mid + 1;
        else hi = mid;
    }
    return lo;
}

// ---- segmented mean-pool stage 1: partial sums over bf16 h ----
__global__ __launch_bounds__(256) void pool_partial_kernel(const ushort* __restrict__ h,
                                                           const int* __restrict__ batch,
                                                           float* __restrict__ partials) {
    const int g = blockIdx.x;
    const int p = blockIdx.y;
    const int c = threadIdx.x;
    const int lo = lower_bound_batch(batch, g);
    const int hi = lower_bound_batch(batch, g + 1);
    const int cnt = hi - lo;
    const int chunk = (cnt + PP - 1) / PP;
    const int n0 = lo + p * chunk;
    const int n1 = min(hi, n0 + chunk);
    float sum = 0.0f;
    for (int n = n0; n < n1; n++) sum += bf2f(h[(size_t)n * HIDC + c]);
    partials[((size_t)g * PP + p) * HIDC + c] = sum;
}

// ---- stage 2: reduce partials, mean, head linear (fp32) ----
__global__ __launch_bounds__(256) void head_kernel(const float* __restrict__ partials,
                                                   const int* __restrict__ batch,
                                                   const float* __restrict__ Wl,
                                                   const float* __restrict__ bl,
                                                   float* __restrict__ out) {
    __shared__ float s[HIDC];
    const int g = blockIdx.x;
    const int c = threadIdx.x;
    const int lo = lower_bound_batch(batch, g);
    const int hi = lower_bound_batch(batch, g + 1);
    const float inv = 1.0f / fmaxf((float)(hi - lo), 1.0f);
    float sum = 0.0f;
#pragma unroll
    for (int p = 0; p < PP; p++) sum += partials[((size_t)g * PP + p) * HIDC + c];
    s[c] = sum * inv;
    __syncthreads();
    if (c < OUTC) {
        float acc = bl[c];
        for (int k = 0; k < HIDC; k++) acc += s[k] * Wl[(size_t)c * HIDC + k];
        out[(size_t)g * OUTC + c] = acc;
    }
}

extern "C" void kernel_launch(void* const* d_in, const int* in_sizes, int n_in,
                              void* d_out, int out_size, void* d_ws, size_t ws_size,
                              hipStream_t stream) {
    const float* x     = (const float*)d_in[0];
    const int*   ei    = (const int*)d_in[1];
    const int*   batch = (const int*)d_in[2];
    const float* ew    = (const float*)d_in[3];
    const float* W1    = (const float*)d_in[4];
    const float* b1    = (const float*)d_in[5];
    const float* W2    = (const float*)d_in[6];
    const float* b2    = (const float*)d_in[7];
    const float* W3    = (const float*)d_in[8];
    const float* b3    = (const float*)d_in[9];
    const float* Wl    = (const float*)d_in[10];
    const float* bl    = (const float*)d_in[11];

    // ---- workspace layout (no aliasing; ~40 MB of 268 MB) ----
    char* p = (char*)d_ws;
    uint2*  stag   = (uint2*)p;  p += (size_t)G1 * NB * CAPB * 8;   // 20.6 MB
    ushort* xb     = (ushort*)p; p += (size_t)NN * INC * 2;
    ushort* agg128 = (ushort*)p; p += (size_t)NN * INC * 2;
    ushort* agg256 = (ushort*)p; p += (size_t)NN * HIDC * 2;
    ushort* h      = (ushort*)p; p += (size_t)NN * HIDC * 2;
    uint*   erec   = (uint*)p;   p += (size_t)NE * 4;
    float*  partials = (float*)p; p += (size_t)NG * PP * HIDC * 4;
    int*    cnts   = (int*)p;    p += (size_t)G1 * NB * 4;
    int*    cnts_T = (int*)p;    p += (size_t)NB * G1 * 4;
    int*    bucket_start = (int*)p; p += 1024;
    int*    row_start = (int*)p; p += 40016;

    // ---- CSR build: radix partition (per call) ----
    partition_kernel<<<G1, 256, 0, stream>>>(ei, ew, stag, cnts, cnts_T, x, xb);
    bucketscan_kernel<<<1, 256, 0, stream>>>(cnts_T, bucket_start, row_start);
    place_kernel<<<NB, 256, 0, stream>>>(stag, cnts, bucket_start, row_start, erec);

    const int gather_grid = (NN + 3) / 4;
    dim3 gemm_grid((NN + 127) / 128, HIDC / 64);

    // ---- layer 1 (K=128) ----
    gather_bf16_kernel<INC><<<gather_grid, 256, 0, stream>>>(row_start, erec, xb, agg128);
    mfma_gemm_kernel<INC><<<gemm_grid, 256, 0, stream>>>(agg128, W1, b1, h, NN);

    // ---- layer 2 (K=256) ----
    gather_bf16_kernel<HIDC><<<gather_grid, 256, 0, stream>>>(row_start, erec, h, agg256);
    mfma_gemm_kernel<HIDC><<<gemm_grid, 256, 0, stream>>>(agg256, W2, b2, h, NN);

    // ---- layer 3 (K=256) ----
    gather_bf16_kernel<HIDC><<<gather_grid, 256, 0, stream>>>(row_start, erec, h, agg256);
    mfma_gemm_kernel<HIDC><<<gemm_grid, 256, 0, stream>>>(agg256, W3, b3, h, NN);

    // ---- global mean pool + head ----
    pool_partial_kernel<<<dim3(NG, PP), 256, 0, stream>>>(h, batch, partials);
    head_kernel<<<NG, 256, 0, stream>>>(partials, batch, Wl, bl, (float*)d_out);
}

// Round 11
// 242.301 us; speedup vs baseline: 1.6983x; 1.0786x over previous
//
#include <hip/hip_runtime.h>
#include <hip/hip_fp16.h>

namespace {
constexpr int NN   = 10000;   // nodes
constexpr int NE   = 640000;  // edges
constexpr int INC  = 128;     // input channels
constexpr int HIDC = 256;     // hidden channels
constexpr int OUTC = 10;      // output channels
constexpr int NG   = 64;      // graphs
constexpr int PP   = 8;       // pooling partials per graph

// radix-partition CSR build
constexpr int NB     = 157;       // dst buckets of 64 nodes (bucket = dst>>6)
constexpr int G1     = 256;       // partition blocks
constexpr int CHUNK1 = NE / G1;   // 2500 edges per partition block
constexpr int CAPB   = 64;        // per (block,bucket) fragment cap (mean 16, +12 sigma)
constexpr int LCAP   = 5120;      // place LDS record cache (bucket mean 4076, +16 sigma)
}

typedef __attribute__((ext_vector_type(8))) short short8;
typedef __attribute__((ext_vector_type(4))) float f32x4;

__device__ __forceinline__ ushort f2bf(float f) {
    uint u = __float_as_uint(f);
    uint r = u + 0x7FFFu + ((u >> 16) & 1u);   // RNE
    return (ushort)(r >> 16);
}
__device__ __forceinline__ float bf2f(ushort u) {
    return __uint_as_float(((uint)u) << 16);
}
__device__ __forceinline__ float rec_w(uint rec) {
    return __half2float(__ushort_as_half((ushort)(rec & 0xFFFFu)));
}

// ---- CSR pass 1: partition edges into block-private per-bucket fragments ----
// Record: {x = (src<<16)|half(w), y = dst}. Fused tail: x fp32 -> bf16.
__global__ __launch_bounds__(256) void partition_kernel(const int* __restrict__ ei,
                                                        const float* __restrict__ ew,
                                                        uint2* __restrict__ stag,
                                                        int* __restrict__ cnts,
                                                        int* __restrict__ cnts_T,
                                                        const float* __restrict__ x,
                                                        ushort* __restrict__ xb) {
    __shared__ int lcnt[NB];
    const int t = threadIdx.x, g = blockIdx.x;
    for (int i = t; i < NB; i += 256) lcnt[i] = 0;
    __syncthreads();
    const int base = g * CHUNK1;
    for (int i = t; i < CHUNK1; i += 256) {
        const int e = base + i;
        const int dst = ei[NE + e];
        const int src = ei[e];
        const ushort hw = __half_as_ushort(__float2half(ew[e]));
        const int bk = dst >> 6;
        const int idx = atomicAdd(&lcnt[bk], 1);
        if (idx < CAPB)
            stag[((size_t)g * NB + bk) * CAPB + idx] =
                make_uint2(((uint)src << 16) | (uint)hw, (uint)dst);
    }
    __syncthreads();
    for (int i = t; i < NB; i += 256) {
        const int c = min(lcnt[i], CAPB);
        cnts[g * NB + i] = c;          // g-major: read by place foff scan
        cnts_T[i * G1 + g] = c;        // b-major: contiguous rows for bucket totals
    }
    // fused: x fp32 -> bf16 (independent of staging)
    const int total4 = NN * INC / 4;
    for (int i = g * 256 + t; i < total4; i += G1 * 256) {
        float4 v = ((const float4*)x)[i];
        ushort4 o;
        o.x = f2bf(v.x); o.y = f2bf(v.y); o.z = f2bf(v.z); o.w = f2bf(v.w);
        ((ushort4*)xb)[i] = o;
    }
}

// ---- CSR pass 2: per-bucket counting sort (fused bucket prefix) ----
// 1024 threads/block, one block per bucket. Single global read of the
// bucket's records (LDS-cached); all erec writes land in the bucket's
// contiguous segment -> dense lines.
__global__ __launch_bounds__(1024) void place_kernel(const uint2* __restrict__ stag,
                                                     const int* __restrict__ cnts,
                                                     const int* __restrict__ cnts_T,
                                                     int* __restrict__ row_start,
                                                     uint* __restrict__ erec) {
    const int b = blockIdx.x;
    const int t = threadIdx.x;
    __shared__ int part[256];
    __shared__ int foff[G1 + 1];
    __shared__ int h[64];
    __shared__ int curl[64];
    __shared__ uint2 srec[LCAP];

    // Phase 0: bucket totals (contiguous int4 rows) -> exclusive prefix -> bs
    {
        int s = 0;
        if (t < NB) {
            const int4* r = (const int4*)(cnts_T + (size_t)t * G1);
#pragma unroll 8
            for (int i = 0; i < G1 / 4; i++) {
                int4 v = r[i];
                s += v.x + v.y + v.z + v.w;
            }
        }
        if (t < 256) part[t] = s;
        __syncthreads();
        for (int off = 1; off < 256; off <<= 1) {
            int v = 0;
            if (t < 256 && t >= off) v = part[t - off];
            __syncthreads();
            if (t < 256) part[t] += v;
            __syncthreads();
        }
    }
    const int bs = (b == 0) ? 0 : part[b - 1];
    if (b == 0 && t == 0) row_start[NN] = part[NB - 1];
    __syncthreads();

    // Phase 1: fragment offsets within this bucket (scan of cnts[:, b])
    {
        int c = 0;
        if (t < 256) c = cnts[t * NB + b];
        if (t < 256) part[t] = c;
        if (t < 64) h[t] = 0;
        __syncthreads();
        for (int off = 1; off < 256; off <<= 1) {
            int v = 0;
            if (t < 256 && t >= off) v = part[t - off];
            __syncthreads();
            if (t < 256) part[t] += v;
            __syncthreads();
        }
        if (t < 256) foff[t] = part[t] - c;
        if (t == 0) foff[G1] = part[255];
        __syncthreads();
    }
    const int Rb = foff[G1];

    // Phase 2: single global pass: records -> LDS cache + dst_low histogram
    for (int r = t; r < Rb; r += 1024) {
        int lo = 0, hi = G1;
        while (hi - lo > 1) { int mid = (lo + hi) >> 1; if (foff[mid] <= r) lo = mid; else hi = mid; }
        uint2 rec = stag[((size_t)lo * NB + b) * CAPB + (r - foff[lo])];
        if (r < LCAP) srec[r] = rec;
        atomicAdd(&h[rec.y & 63], 1);
    }
    __syncthreads();

    // Phase 3: scan h -> node offsets; emit row_start for this bucket's nodes
    {
        const int hv = (t < 64) ? h[t] : 0;
        if (t < 256) part[t] = (t < 64) ? hv : 0;
        __syncthreads();
        for (int off = 1; off < 64; off <<= 1) {
            int v = 0;
            if (t < 256 && t >= off) v = part[t - off];
            __syncthreads();
            if (t < 256) part[t] += v;
            __syncthreads();
        }
        if (t < 64) {
            const int excl = part[t] - hv;
            const int node = b * 64 + t;
            if (node < NN) row_start[node] = bs + excl;
            curl[t] = excl;
        }
        __syncthreads();
    }

    // Phase 4: place records (LDS-resident; global fallback for overflow)
    for (int r = t; r < Rb; r += 1024) {
        uint2 rec;
        if (r < LCAP) rec = srec[r];
        else {
            int lo = 0, hi = G1;
            while (hi - lo > 1) { int mid = (lo + hi) >> 1; if (foff[mid] <= r) lo = mid; else hi = mid; }
            rec = stag[((size_t)lo * NB + b) * CAPB + (r - foff[lo])];
        }
        const int pos = bs + atomicAdd(&curl[rec.y & 63], 1);
        erec[pos] = rec.x;
    }
}

// ---- aggregation gather, full row (used for F=128) ----
template <int F>
__global__ __launch_bounds__(256) void gather_bf16_kernel(const int* __restrict__ row_start,
                                                          const uint* __restrict__ erec,
                                                          const ushort* __restrict__ x,
                                                          ushort* __restrict__ out) {
    constexpr int VEC = F / 64;
    constexpr int U = 12;
    const int n = blockIdx.x * 4 + (threadIdx.x >> 6);
    const int lane = threadIdx.x & 63;
    if (n >= NN) return;
    const int beg = row_start[n];
    const int end = row_start[n + 1];
    const size_t loff = (size_t)lane * VEC;

    float acc[VEC];
    {
        ushort v[VEC];
        if (VEC == 4) *(ushort4*)v = *(const ushort4*)(x + (size_t)n * F + loff);
        else          *(ushort2*)v = *(const ushort2*)(x + (size_t)n * F + loff);
#pragma unroll
        for (int i = 0; i < VEC; i++) acc[i] = bf2f(v[i]);
    }

    int e = beg;
    for (; e + U <= end; e += U) {
        uint rec[U];
#pragma unroll
        for (int u = 0; u < U; u++) rec[u] = erec[e + u];
        ushort v[U][VEC];
#pragma unroll
        for (int u = 0; u < U; u++) {
            const ushort* r = x + (size_t)(rec[u] >> 16) * F + loff;
            if (VEC == 4) *(ushort4*)v[u] = *(const ushort4*)r;
            else          *(ushort2*)v[u] = *(const ushort2*)r;
        }
#pragma unroll
        for (int u = 0; u < U; u++) {
            const float w = rec_w(rec[u]);
#pragma unroll
            for (int i = 0; i < VEC; i++) acc[i] += w * bf2f(v[u][i]);
        }
    }
    for (; e < end; e++) {
        uint rec = erec[e];
        const float w = rec_w(rec);
        ushort v[VEC];
        const ushort* r = x + (size_t)(rec >> 16) * F + loff;
        if (VEC == 4) *(ushort4*)v = *(const ushort4*)r;
        else          *(ushort2*)v = *(const ushort2*)r;
#pragma unroll
        for (int i = 0; i < VEC; i++) acc[i] += w * bf2f(v[i]);
    }

    ushort o[VEC];
#pragma unroll
    for (int i = 0; i < VEC; i++) o[i] = f2bf(acc[i]);
    if (VEC == 4) *(ushort4*)(out + (size_t)n * F + loff) = *(ushort4*)o;
    else          *(ushort2*)(out + (size_t)n * F + loff) = *(ushort2*)o;
}

// ---- F=256 gather, column-split: blockIdx.y selects 128-channel half ----
// Each half's working set is 2.56 MB -> fits the 4-MB per-XCD L2.
__global__ __launch_bounds__(256) void gather_bf16_half_kernel(const int* __restrict__ row_start,
                                                               const uint* __restrict__ erec,
                                                               const ushort* __restrict__ x,
                                                               ushort* __restrict__ out) {
    constexpr int U = 16;
    const int n = blockIdx.x * 4 + (threadIdx.x >> 6);
    const int lane = threadIdx.x & 63;
    if (n >= NN) return;
    const int beg = row_start[n];
    const int end = row_start[n + 1];
    const size_t loff = (size_t)blockIdx.y * 128 + lane * 2;

    float acc[2];
    {
        ushort2 v = *(const ushort2*)(x + (size_t)n * HIDC + loff);
        acc[0] = bf2f(v.x);
        acc[1] = bf2f(v.y);
    }

    int e = beg;
    for (; e + U <= end; e += U) {
        uint rec[U];
#pragma unroll
        for (int u = 0; u < U; u++) rec[u] = erec[e + u];
        ushort2 v[U];
#pragma unroll
        for (int u = 0; u < U; u++)
            v[u] = *(const ushort2*)(x + (size_t)(rec[u] >> 16) * HIDC + loff);
#pragma unroll
        for (int u = 0; u < U; u++) {
            const float w = rec_w(rec[u]);
            acc[0] += w * bf2f(v[u].x);
            acc[1] += w * bf2f(v[u].y);
        }
    }
    for (; e < end; e++) {
        uint rec = erec[e];
        const float w = rec_w(rec);
        ushort2 v = *(const ushort2*)(x + (size_t)(rec >> 16) * HIDC + loff);
        acc[0] += w * bf2f(v.x);
        acc[1] += w * bf2f(v.y);
    }

    ushort2 o;
    o.x = f2bf(acc[0]);
    o.y = f2bf(acc[1]);
    *(ushort2*)(out + (size_t)n * HIDC + loff) = o;
}

// ---- MFMA bf16 GEMM: C[M,256] = relu(A[M,K] @ W[256,K]^T + bias), bf16 out ----
template <int K>
__global__ __launch_bounds__(256) void mfma_gemm_kernel(const ushort* __restrict__ A,
                                                        const float* __restrict__ W,
                                                        const float* __restrict__ bias,
                                                        ushort* __restrict__ C, int M) {
    constexpr int LDW = K + 8;
    __shared__ ushort Ws[64 * LDW];
    const int tid = threadIdx.x;
    const int bm = blockIdx.x * 128;
    const int bn = blockIdx.y * 64;

    constexpr int CPR = K / 4;
    for (int idx = tid; idx < 64 * CPR; idx += 256) {
        int r = idx / CPR, c = idx % CPR;
        float4 v = *(const float4*)(W + (size_t)(bn + r) * K + c * 4);
        ushort4 o;
        o.x = f2bf(v.x); o.y = f2bf(v.y); o.z = f2bf(v.z); o.w = f2bf(v.w);
        *(ushort4*)(&Ws[r * LDW + c * 4]) = o;
    }
    __syncthreads();

    const int wave = tid >> 6;
    const int lane = tid & 63;
    const int lrow = lane & 15;
    const int lq   = lane >> 4;
    const int m0 = bm + wave * 32;

    f32x4 acc[2][4] = {};
    const int r0 = min(m0 + lrow, M - 1);
    const int r1 = min(m0 + 16 + lrow, M - 1);

    for (int k0 = 0; k0 < K; k0 += 32) {
        const int kk = k0 + lq * 8;
        short8 a0 = *(const short8*)(A + (size_t)r0 * K + kk);
        short8 a1 = *(const short8*)(A + (size_t)r1 * K + kk);
        short8 b[4];
#pragma unroll
        for (int j = 0; j < 4; j++)
            b[j] = *(const short8*)(&Ws[(j * 16 + lrow) * LDW + kk]);
#pragma unroll
        for (int j = 0; j < 4; j++) {
            acc[0][j] = __builtin_amdgcn_mfma_f32_16x16x32_bf16(a0, b[j], acc[0][j], 0, 0, 0);
            acc[1][j] = __builtin_amdgcn_mfma_f32_16x16x32_bf16(a1, b[j], acc[1][j], 0, 0, 0);
        }
    }

#pragma unroll
    for (int sub = 0; sub < 2; sub++) {
#pragma unroll
        for (int j = 0; j < 4; j++) {
            const int gn = bn + j * 16 + lrow;
            const float bv = bias[gn];
#pragma unroll
            for (int i = 0; i < 4; i++) {
                const int gm = m0 + sub * 16 + lq * 4 + i;
                if (gm < M) {
                    float v = acc[sub][j][i] + bv;
                    v = fmaxf(v, 0.0f);
                    C[(size_t)gm * HIDC + gn] = f2bf(v);
                }
            }
        }
    }
}

__device__ __forceinline__ int lower_bound_batch(const int* __restrict__ batch, int val) {
    int lo = 0, hi = NN;
    while (lo < hi) {
        int mid = (lo + hi) >> 1;
        if (batch[mid] < val) lo = mid + 1;
        else hi = mid;
    }
    return lo;
}

// ---- segmented mean-pool stage 1: partial sums over bf16 h ----
__global__ __launch_bounds__(256) void pool_partial_kernel(const ushort* __restrict__ h,
                                                           const int* __restrict__ batch,
                                                           float* __restrict__ partials) {
    const int g = blockIdx.x;
    const int p = blockIdx.y;
    const int c = threadIdx.x;
    const int lo = lower_bound_batch(batch, g);
    const int hi = lower_bound_batch(batch, g + 1);
    const int cnt = hi - lo;
    const int chunk = (cnt + PP - 1) / PP;
    const int n0 = lo + p * chunk;
    const int n1 = min(hi, n0 + chunk);
    float sum = 0.0f;
    for (int n = n0; n < n1; n++) sum += bf2f(h[(size_t)n * HIDC + c]);
    partials[((size_t)g * PP + p) * HIDC + c] = sum;
}

// ---- stage 2: reduce partials, mean, head linear (fp32) ----
__global__ __launch_bounds__(256) void head_kernel(const float* __restrict__ partials,
                                                   const int* __restrict__ batch,
                                                   const float* __restrict__ Wl,
                                                   const float* __restrict__ bl,
                                                   float* __restrict__ out) {
    __shared__ float s[HIDC];
    const int g = blockIdx.x;
    const int c = threadIdx.x;
    const int lo = lower_bound_batch(batch, g);
    const int hi = lower_bound_batch(batch, g + 1);
    const float inv = 1.0f / fmaxf((float)(hi - lo), 1.0f);
    float sum = 0.0f;
#pragma unroll
    for (int p = 0; p < PP; p++) sum += partials[((size_t)g * PP + p) * HIDC + c];
    s[c] = sum * inv;
    __syncthreads();
    if (c < OUTC) {
        float acc = bl[c];
        for (int k = 0; k < HIDC; k++) acc += s[k] * Wl[(size_t)c * HIDC + k];
        out[(size_t)g * OUTC + c] = acc;
    }
}

extern "C" void kernel_launch(void* const* d_in, const int* in_sizes, int n_in,
                              void* d_out, int out_size, void* d_ws, size_t ws_size,
                              hipStream_t stream) {
    const float* x     = (const float*)d_in[0];
    const int*   ei    = (const int*)d_in[1];
    const int*   batch = (const int*)d_in[2];
    const float* ew    = (const float*)d_in[3];
    const float* W1    = (const float*)d_in[4];
    const float* b1    = (const float*)d_in[5];
    const float* W2    = (const float*)d_in[6];
    const float* b2    = (const float*)d_in[7];
    const float* W3    = (const float*)d_in[8];
    const float* b3    = (const float*)d_in[9];
    const float* Wl    = (const float*)d_in[10];
    const float* bl    = (const float*)d_in[11];

    // ---- workspace layout ----
    char* p = (char*)d_ws;
    uint2*  stag   = (uint2*)p;  p += (size_t)G1 * NB * CAPB * 8;   // 20.6 MB
    ushort* xb     = (ushort*)p; p += (size_t)NN * INC * 2;
    ushort* agg128 = (ushort*)p; p += (size_t)NN * INC * 2;
    ushort* agg256 = (ushort*)p; p += (size_t)NN * HIDC * 2;
    ushort* h      = (ushort*)p; p += (size_t)NN * HIDC * 2;
    uint*   erec   = (uint*)p;   p += (size_t)NE * 4;
    float*  partials = (float*)p; p += (size_t)NG * PP * HIDC * 4;
    int*    cnts   = (int*)p;    p += (size_t)G1 * NB * 4;
    int*    cnts_T = (int*)p;    p += (size_t)NB * G1 * 4;
    int*    row_start = (int*)p; p += 40016;

    // ---- CSR build: radix partition (per call) ----
    partition_kernel<<<G1, 256, 0, stream>>>(ei, ew, stag, cnts, cnts_T, x, xb);
    place_kernel<<<NB, 1024, 0, stream>>>(stag, cnts, cnts_T, row_start, erec);

    const int gather_grid = (NN + 3) / 4;
    dim3 gemm_grid((NN + 127) / 128, HIDC / 64);

    // ---- layer 1 (K=128) ----
    gather_bf16_kernel<INC><<<gather_grid, 256, 0, stream>>>(row_start, erec, xb, agg128);
    mfma_gemm_kernel<INC><<<gemm_grid, 256, 0, stream>>>(agg128, W1, b1, h, NN);

    // ---- layer 2 (K=256) ----
    gather_bf16_half_kernel<<<dim3(gather_grid, 2), 256, 0, stream>>>(row_start, erec, h, agg256);
    mfma_gemm_kernel<HIDC><<<gemm_grid, 256, 0, stream>>>(agg256, W2, b2, h, NN);

    // ---- layer 3 (K=256) ----
    gather_bf16_half_kernel<<<dim3(gather_grid, 2), 256, 0, stream>>>(row_start, erec, h, agg256);
    mfma_gemm_kernel<HIDC><<<gemm_grid, 256, 0, stream>>>(agg256, W3, b3, h, NN);

    // ---- global mean pool + head ----
    pool_partial_kernel<<<dim3(NG, PP), 256, 0, stream>>>(h, batch, partials);
    head_kernel<<<NG, 256, 0, stream>>>(partials, batch, Wl, bl, (float*)d_out);
}